// Round 5
// baseline (356.270 us; speedup 1.0000x reference)
//
#include <hip/hip_runtime.h>

typedef __bf16 bf16;
typedef bf16 bf16x8 __attribute__((ext_vector_type(8)));
typedef bf16 bf16x4 __attribute__((ext_vector_type(4)));
typedef float f32x4 __attribute__((ext_vector_type(4)));

#define ASYNC16(gp, lp) __builtin_amdgcn_global_load_lds( \
    (__attribute__((address_space(1))) void*)(const void*)(gp), \
    (__attribute__((address_space(3))) void*)(lp), 16, 0, 0)

__device__ __forceinline__ bf16x8 cvt2(const float4 a, const float4 b) {
    bf16x8 t;
    t[0] = (bf16)a.x; t[1] = (bf16)a.y; t[2] = (bf16)a.z; t[3] = (bf16)a.w;
    t[4] = (bf16)b.x; t[5] = (bf16)b.y; t[6] = (bf16)b.z; t[7] = (bf16)b.w;
    return t;
}

// =====================================================================
// fp32 -> bf16 weight converters
// =====================================================================
__global__ __launch_bounds__(256)
void cvt_w1(const float* __restrict__ W, bf16* __restrict__ out)
{
    const int i = blockIdx.x * 256 + threadIdx.x;
    const float4 a = ((const float4*)W)[i * 2];
    const float4 b = ((const float4*)W)[i * 2 + 1];
    *(bf16x8*)&out[(size_t)i * 8] = cvt2(a, b);
}

__global__ __launch_bounds__(256)
void cvt_w3(const float* __restrict__ W0, const float* __restrict__ W1,
            const float* __restrict__ W2, bf16* __restrict__ out)
{
    const int z = blockIdx.y;
    const float* src = (z == 0) ? W0 : (z == 1) ? W1 : W2;
    const int i = blockIdx.x * 256 + threadIdx.x;          // < 131072
    const float4 a = ((const float4*)src)[i * 2];
    const float4 b = ((const float4*)src)[i * 2 + 1];
    *(bf16x8*)&out[((size_t)z << 20) + (size_t)i * 8] = cvt2(a, b);
}

// =====================================================================
// Merged projection GEMM, 128x64 tiles (N-split for 2x block count:
// the 2-barrier structure hides latency via co-resident blocks, and at
// 128x128 the grid was only ~4 blocks/CU -> occupancy-starved at 17%).
// grid (16, 64, 3), block 256 (4 waves, 2x2 of 64x32). BK=64 as two
// 32-halves, single-buffered (Round-1 structure: stage, barrier,
// compute, barrier -- known-good 310us baseline).
// A fp32 (q/k/v) staged inline with cvt; W bf16 staged via ASYNC16.
// z=0: Qp = q*Wq^T ; z=1: Kp = k*Wk^T ; z=2: Vt = (v*Wv^T)^T [B,H,d,S]
// Key-mask early-exit for z>=1 (dead Kp/Vt bands), block-uniform,
// precedes all barriers.
// =====================================================================
__global__ __launch_bounds__(256, 2)
void proj_gemm(const float* __restrict__ q, const float* __restrict__ k,
               const float* __restrict__ v, const bf16* __restrict__ Wb3,
               const int* __restrict__ sen_len,
               bf16* __restrict__ Qp, bf16* __restrict__ Kp, bf16* __restrict__ Vt)
{
    constexpr int K = 1024;
    __shared__ __align__(16) bf16 As[2][128 * 32];   // [half][128 x 32]
    __shared__ __align__(16) bf16 Bs[2][64 * 32];    // [half][64 x 32]

    const int z = blockIdx.z;
    const int flat = blockIdx.y * 16 + blockIdx.x;   // 0..1023
    const int m0   = (flat & 63) * 128;              // consecutive blocks same n-panel
    const int n0   = (flat >> 6) * 64;

    // dead-output skip for key/value projections (block-uniform branch)
    if (z != 0) {
        const int s0 = m0 & 2047;
        if (s0 >= sen_len[m0 >> 11]) return;
    }

    const float* A = (z == 0) ? q : (z == 1) ? k : v;
    const bf16* W = Wb3 + ((size_t)z << 20);

    const int tid  = threadIdx.x;
    const int lane = tid & 63;
    const int w    = tid >> 6;
    const int wr   = w >> 1, wc = w & 1;

    f32x4 acc[4][2] = {};

    for (int k0 = 0; k0 < K; k0 += 64) {
        #pragma unroll
        for (int half = 0; half < 2; ++half) {
            const int kbase = k0 + half * 32;
            // B: 64x32 = 256 chunks of 8 elems, 1 per thread (ASYNC16)
            {
                const int c = tid, row = c >> 2, kg = c & 3;
                ASYNC16(W + (size_t)(n0 + row) * K + kbase + kg * 8, &Bs[half][c * 8]);
            }
            // A: 128x32 = 512 chunks, 2 per thread (fp32 load + cvt + ds_write)
            #pragma unroll
            for (int i = 0; i < 2; ++i) {
                const int c = tid + i * 256, row = c >> 2, kg = c & 3;
                const float* ap = A + (size_t)(m0 + row) * K + kbase + kg * 8;
                *(bf16x8*)&As[half][c * 8] = cvt2(*(const float4*)ap, *(const float4*)(ap + 4));
            }
        }
        __syncthreads();
        #pragma unroll
        for (int kk = 0; kk < 2; ++kk) {
            bf16x8 af[4], bfr[2];
            #pragma unroll
            for (int t = 0; t < 4; ++t)
                af[t] = *(const bf16x8*)&As[kk][(wr * 64 + t * 16 + (lane & 15)) * 32 + (lane >> 4) * 8];
            #pragma unroll
            for (int t = 0; t < 2; ++t)
                bfr[t] = *(const bf16x8*)&Bs[kk][(wc * 32 + t * 16 + (lane & 15)) * 32 + (lane >> 4) * 8];
            #pragma unroll
            for (int mt = 0; mt < 4; ++mt)
                #pragma unroll
                for (int nt = 0; nt < 2; ++nt)
                    acc[mt][nt] = __builtin_amdgcn_mfma_f32_16x16x32_bf16(af[mt], bfr[nt], acc[mt][nt], 0, 0, 0);
        }
        __syncthreads();
    }

    // epilogue: D[row][col], row=(lane>>4)*4+r, col=lane&15
    #pragma unroll
    for (int mt = 0; mt < 4; ++mt) {
        #pragma unroll
        for (int nt = 0; nt < 2; ++nt) {
            const int mbase = m0 + wr * 64 + mt * 16 + ((lane >> 4) << 2);
            const int n     = n0 + wc * 32 + nt * 16 + (lane & 15);
            if (z < 2) {
                bf16* out = (z == 0) ? Qp : Kp;     // row-major [M, 1024]
                #pragma unroll
                for (int r = 0; r < 4; ++r)
                    out[(size_t)(mbase + r) * 1024 + n] = (bf16)acc[mt][nt][r];
            } else {
                const int h = n >> 6, dd = n & 63;
                const int b = mbase >> 11, s = mbase & 2047;   // r=0..3 -> s..s+3
                bf16x4 v4;
                #pragma unroll
                for (int r = 0; r < 4; ++r) v4[r] = (bf16)acc[mt][nt][r];
                *(bf16x4*)&Vt[(((size_t)(b * 16 + h)) * 64 + dd) * 2048 + s] = v4;
            }
        }
    }
}

// =====================================================================
// Out-projection GEMM, 128x64 tiles (same N-split rationale: old grid
// was 512 blocks = 2/CU). grid (16, 64), block 256. BK=64 as two
// 32-halves, both operands bf16 via ASYNC16. y = ctx * Wo^T + R.
// =====================================================================
__global__ __launch_bounds__(256, 2)
void gemm_out(const bf16* __restrict__ A, const bf16* __restrict__ W,
              const float* __restrict__ R, float* __restrict__ out)
{
    constexpr int K = 1024;
    __shared__ __align__(16) bf16 As[2][128 * 32];
    __shared__ __align__(16) bf16 Bs[2][64 * 32];

    const int tid  = threadIdx.x;
    const int lane = tid & 63;
    const int w    = tid >> 6;
    const int wr   = w >> 1, wc = w & 1;
    const int flat = blockIdx.y * 16 + blockIdx.x;   // 0..1023
    const int m0   = (flat & 63) * 128;
    const int n0   = (flat >> 6) * 64;

    f32x4 acc[4][2] = {};

    for (int k0 = 0; k0 < K; k0 += 64) {
        #pragma unroll
        for (int half = 0; half < 2; ++half) {
            const int kbase = k0 + half * 32;
            {
                const int c = tid, row = c >> 2, kg = c & 3;
                ASYNC16(W + (size_t)(n0 + row) * K + kbase + kg * 8, &Bs[half][c * 8]);
            }
            #pragma unroll
            for (int i = 0; i < 2; ++i) {
                const int c = tid + i * 256, row = c >> 2, kg = c & 3;
                ASYNC16(A + (size_t)(m0 + row) * K + kbase + kg * 8, &As[half][c * 8]);
            }
        }
        __syncthreads();
        #pragma unroll
        for (int kk = 0; kk < 2; ++kk) {
            bf16x8 af[4], bfr[2];
            #pragma unroll
            for (int t = 0; t < 4; ++t)
                af[t] = *(const bf16x8*)&As[kk][(wr * 64 + t * 16 + (lane & 15)) * 32 + (lane >> 4) * 8];
            #pragma unroll
            for (int t = 0; t < 2; ++t)
                bfr[t] = *(const bf16x8*)&Bs[kk][(wc * 32 + t * 16 + (lane & 15)) * 32 + (lane >> 4) * 8];
            #pragma unroll
            for (int mt = 0; mt < 4; ++mt)
                #pragma unroll
                for (int nt = 0; nt < 2; ++nt)
                    acc[mt][nt] = __builtin_amdgcn_mfma_f32_16x16x32_bf16(af[mt], bfr[nt], acc[mt][nt], 0, 0, 0);
        }
        __syncthreads();
    }

    #pragma unroll
    for (int mt = 0; mt < 4; ++mt) {
        #pragma unroll
        for (int nt = 0; nt < 2; ++nt) {
            const int mbase = m0 + wr * 64 + mt * 16 + ((lane >> 4) << 2);
            const int n     = n0 + wc * 32 + nt * 16 + (lane & 15);
            #pragma unroll
            for (int r = 0; r < 4; ++r) {
                const size_t idx = (size_t)(mbase + r) * 1024 + n;
                out[idx] = acc[mt][nt][r] + R[idx];
            }
        }
    }
}

// =====================================================================
// Flash attention, static-max. block 256 (4 waves), grid (16,16,4).
// Qp,Kp: [B,S,D] bf16 (head-cols h*64..h*64+63); Vt: [B,H,d,S] bf16;
// ctx out: [B,S,H*64] bf16. softmax = exp(S*scale-20)/sum (exact).
// =====================================================================
__global__ __launch_bounds__(256, 2)
void attn_kernel(const bf16* __restrict__ Qp, const bf16* __restrict__ Kp,
                 const bf16* __restrict__ Vt, const int* __restrict__ sen_len,
                 bf16* __restrict__ ctx)
{
    const int qt = gridDim.x - 1 - blockIdx.x;   // longest blocks first
    const int h = blockIdx.y, b = blockIdx.z;
    const int q0 = qt * 128;
    const int slen = sen_len[b];
    const int tid = threadIdx.x, lane = tid & 63, w = tid >> 6;
    const int wr = w >> 1, wc = w & 1;
    const float SCALE = 0.125f;   // 1/sqrt(64)
    const float SHIFT = 20.0f;    // static softmax shift

    __shared__ __align__(16) bf16 Ps[128 * 136];   // [q][k] probs, padded
    __shared__ float psum[2][128];

    // Q fragments (A-operand: m=lane&15, k=(lane>>4)*8+j)
    bf16x8 qf[4][2];
    const bf16* Qbase = Qp + ((size_t)(b * 2048 + q0)) * 1024 + h * 64;
    #pragma unroll
    for (int mt = 0; mt < 4; ++mt)
        #pragma unroll
        for (int kk = 0; kk < 2; ++kk)
            qf[mt][kk] = *(const bf16x8*)(Qbase + (size_t)(wr * 64 + mt * 16 + (lane & 15)) * 1024
                                          + kk * 32 + (lane >> 4) * 8);

    f32x4 o[4][2] = {};
    float lsum[4][4] = {};   // per-lane partial row sums, reduced at end

    const int jlim = min(q0 + 128, slen);
    const int nkt  = (jlim + 127) >> 7;       // >= 1 since slen >= 1

    const bf16* Kbh = Kp + (size_t)b * 2048 * 1024 + h * 64;
    const bf16* Vbh = Vt + (size_t)(b * 16 + h) * 64 * 2048;

    for (int kt = 0; kt < nkt; ++kt) {
        const int k0 = kt * 128;

        // ---- S = Q K^T (K fragments direct from global, 16B/lane) ----
        f32x4 sf[4][4] = {};
        #pragma unroll
        for (int kk = 0; kk < 2; ++kk) {
            bf16x8 bk[4];
            #pragma unroll
            for (int nt = 0; nt < 4; ++nt)
                bk[nt] = *(const bf16x8*)(Kbh + (size_t)(k0 + wc * 64 + nt * 16 + (lane & 15)) * 1024
                                          + kk * 32 + (lane >> 4) * 8);
            #pragma unroll
            for (int mt = 0; mt < 4; ++mt)
                #pragma unroll
                for (int nt = 0; nt < 4; ++nt)
                    sf[mt][nt] = __builtin_amdgcn_mfma_f32_16x16x32_bf16(qf[mt][kk], bk[nt], sf[mt][nt], 0, 0, 0);
        }

        // ---- P = exp(S*scale - 20); accumulate l; store P to LDS ----
        if (kt == nkt - 1) {
            #pragma unroll
            for (int mt = 0; mt < 4; ++mt)
                #pragma unroll
                for (int r = 0; r < 4; ++r) {
                    const int row = wr * 64 + mt * 16 + ((lane >> 4) << 2) + r;
                    const int ig = q0 + row;
                    #pragma unroll
                    for (int nt = 0; nt < 4; ++nt) {
                        const int jg = k0 + wc * 64 + nt * 16 + (lane & 15);
                        const float sv = (jg > ig || jg >= slen) ? -1.0e9f : sf[mt][nt][r];
                        const float p = __expf(fmaf(sv, SCALE, -SHIFT));
                        lsum[mt][r] += p;
                        Ps[row * 136 + wc * 64 + nt * 16 + (lane & 15)] = (bf16)p;
                    }
                }
        } else {
            #pragma unroll
            for (int mt = 0; mt < 4; ++mt)
                #pragma unroll
                for (int r = 0; r < 4; ++r) {
                    const int row = wr * 64 + mt * 16 + ((lane >> 4) << 2) + r;
                    #pragma unroll
                    for (int nt = 0; nt < 4; ++nt) {
                        const float p = __expf(fmaf(sf[mt][nt][r], SCALE, -SHIFT));
                        lsum[mt][r] += p;
                        Ps[row * 136 + wc * 64 + nt * 16 + (lane & 15)] = (bf16)p;
                    }
                }
        }
        __syncthreads();   // Ps ready for PV

        // ---- O += P V (V fragments direct from global, 16B/lane) ----
        #pragma unroll
        for (int ks = 0; ks < 4; ++ks) {
            bf16x8 pf[4], vf[2];
            #pragma unroll
            for (int mt = 0; mt < 4; ++mt)
                pf[mt] = *(const bf16x8*)&Ps[(wr * 64 + mt * 16 + (lane & 15)) * 136
                                             + ks * 32 + (lane >> 4) * 8];
            #pragma unroll
            for (int nt = 0; nt < 2; ++nt)
                vf[nt] = *(const bf16x8*)(Vbh + (size_t)(wc * 32 + nt * 16 + (lane & 15)) * 2048
                                          + k0 + ks * 32 + (lane >> 4) * 8);
            #pragma unroll
            for (int mt = 0; mt < 4; ++mt)
                #pragma unroll
                for (int nt = 0; nt < 2; ++nt)
                    o[mt][nt] = __builtin_amdgcn_mfma_f32_16x16x32_bf16(pf[mt], vf[nt], o[mt][nt], 0, 0, 0);
        }
        __syncthreads();   // protect Ps for next iteration
    }

    // ---- one-time l reduction ----
    #pragma unroll
    for (int off = 1; off < 16; off <<= 1)
        #pragma unroll
        for (int mt = 0; mt < 4; ++mt)
            #pragma unroll
            for (int r = 0; r < 4; ++r)
                lsum[mt][r] += __shfl_xor(lsum[mt][r], off, 64);
    if ((lane & 15) == 0)
        #pragma unroll
        for (int mt = 0; mt < 4; ++mt)
            #pragma unroll
            for (int r = 0; r < 4; ++r)
                psum[wc][wr * 64 + mt * 16 + ((lane >> 4) << 2) + r] = lsum[mt][r];
    __syncthreads();

    // ---- epilogue: ctx[b, s, h*64+dd] = O / l ----
    #pragma unroll
    for (int mt = 0; mt < 4; ++mt)
        #pragma unroll
        for (int r = 0; r < 4; ++r) {
            const int row = wr * 64 + mt * 16 + ((lane >> 4) << 2) + r;
            const float inv = 1.0f / (psum[0][row] + psum[1][row]);
            const int sg = q0 + row;
            #pragma unroll
            for (int nt = 0; nt < 2; ++nt) {
                const int dd = wc * 32 + nt * 16 + (lane & 15);
                ctx[((size_t)(b * 2048 + sg)) * 1024 + h * 64 + dd] = (bf16)(o[mt][nt][r] * inv);
            }
        }
}

// =====================================================================
// LayerNorm over D=1024; fp32 in/out. grid 8192, block 256.
// =====================================================================
__global__ __launch_bounds__(256)
void ln_kernel(const float* __restrict__ y, const float* __restrict__ gamma,
               const float* __restrict__ beta, float* __restrict__ out)
{
    const int row = blockIdx.x;
    const int tid = threadIdx.x;
    const float4 v = ((const float4*)(y + (size_t)row * 1024))[tid];
    float s  = v.x + v.y + v.z + v.w;
    float s2 = v.x * v.x + v.y * v.y + v.z * v.z + v.w * v.w;
    #pragma unroll
    for (int o = 32; o > 0; o >>= 1) {
        s  += __shfl_down(s, o, 64);
        s2 += __shfl_down(s2, o, 64);
    }
    __shared__ float ps[4], ps2[4], stat[2];
    const int w = tid >> 6, lane = tid & 63;
    if (lane == 0) { ps[w] = s; ps2[w] = s2; }
    __syncthreads();
    if (tid == 0) {
        const float S  = ps[0] + ps[1] + ps[2] + ps[3];
        const float S2 = ps2[0] + ps2[1] + ps2[2] + ps2[3];
        const float mean = S * (1.0f / 1024.0f);
        const float var  = S2 * (1.0f / 1024.0f) - mean * mean;
        stat[0] = mean;
        stat[1] = rsqrtf(var + 1e-5f);
    }
    __syncthreads();
    const float mean = stat[0], rstd = stat[1];
    const float4 g4 = ((const float4*)gamma)[tid];
    const float4 b4 = ((const float4*)beta)[tid];
    float4 ov;
    ov.x = (v.x - mean) * rstd * g4.x + b4.x;
    ov.y = (v.y - mean) * rstd * g4.y + b4.y;
    ov.z = (v.z - mean) * rstd * g4.z + b4.z;
    ov.w = (v.w - mean) * rstd * g4.w + b4.w;
    ((float4*)(out + (size_t)row * 1024))[tid] = ov;
}

// =====================================================================
// Workspace map (peak 56.4 MB):
//   ws[0,SEG):       Qp [B,S,D] -> y fp32 [0,2SEG) after attn
//   ws[SEG,2SEG):    Kp [B,S,D]
//   ws[2SEG,3SEG):   Vt [B,H,d,S]
//   ws[3SEG,+6MB):   Wb3 (Wq,Wk,Wv bf16); first 2MB reused as WoB later
//   d_out[0,SEG):    ctx (attn out) -> final LN out (LN rewrites all d_out)
// =====================================================================
extern "C" void kernel_launch(void* const* d_in, const int* in_sizes, int n_in,
                              void* d_out, int out_size, void* d_ws, size_t ws_size,
                              hipStream_t stream)
{
    const float* q     = (const float*)d_in[0];
    const float* k     = (const float*)d_in[1];
    const float* v     = (const float*)d_in[2];
    const float* Wq    = (const float*)d_in[3];
    const float* Wk    = (const float*)d_in[4];
    const float* Wv    = (const float*)d_in[5];
    const float* Wo    = (const float*)d_in[6];
    const float* gamma = (const float*)d_in[7];
    const float* beta  = (const float*)d_in[8];
    const int*   sen   = (const int*)d_in[9];

    char* ws = (char*)d_ws;
    const size_t SEG = 16777216;             // 8192*1024*2 bytes
    bf16* Qp  = (bf16*)(ws);
    bf16* Kp  = (bf16*)(ws + SEG);
    bf16* Vt  = (bf16*)(ws + 2 * SEG);
    bf16* Wb3 = (bf16*)(ws + 3 * SEG);
    bf16* WoB = (bf16*)(ws + 3 * SEG);       // reuses Wb3 (dead after proj)
    float* y  = (float*)ws;                  // overwrites Qp/Kp after attn
    bf16* ctx = (bf16*)d_out;                // d_out as scratch; LN rewrites

    dim3 bb(256);
    cvt_w3<<<dim3(512, 3), bb, 0, stream>>>(Wq, Wk, Wv, Wb3);
    proj_gemm<<<dim3(16, 64, 3), bb, 0, stream>>>(q, k, v, Wb3, sen, Qp, Kp, Vt);
    attn_kernel<<<dim3(16, 16, 4), bb, 0, stream>>>(Qp, Kp, Vt, sen, ctx);
    cvt_w1<<<dim3(512), bb, 0, stream>>>(Wo, WoB);
    gemm_out<<<dim3(16, 64), bb, 0, stream>>>(ctx, WoB, q, y);
    ln_kernel<<<dim3(8192), bb, 0, stream>>>(y, gamma, beta, (float*)d_out);
}

// Round 7
// 331.026 us; speedup vs baseline: 1.0763x; 1.0763x over previous
//
#include <hip/hip_runtime.h>

typedef __bf16 bf16;
typedef bf16 bf16x8 __attribute__((ext_vector_type(8)));
typedef bf16 bf16x4 __attribute__((ext_vector_type(4)));
typedef float f32x4 __attribute__((ext_vector_type(4)));

#define ASYNC16(gp, lp) __builtin_amdgcn_global_load_lds( \
    (__attribute__((address_space(1))) void*)(const void*)(gp), \
    (__attribute__((address_space(3))) void*)(lp), 16, 0, 0)

// counted waits + raw barrier (no compiler-inserted vmcnt(0) drain)
#define S_VMCNT(N) asm volatile("s_waitcnt vmcnt(" #N ")" ::: "memory")
#define S_LGKM0    asm volatile("s_waitcnt lgkmcnt(0)" ::: "memory")
#define S_BAR      __builtin_amdgcn_s_barrier()

__device__ __forceinline__ bf16x8 cvt2(const float4 a, const float4 b) {
    bf16x8 t;
    t[0] = (bf16)a.x; t[1] = (bf16)a.y; t[2] = (bf16)a.z; t[3] = (bf16)a.w;
    t[4] = (bf16)b.x; t[5] = (bf16)b.y; t[6] = (bf16)b.z; t[7] = (bf16)b.w;
    return t;
}

// =====================================================================
// fp32 -> bf16 weight converters
// =====================================================================
__global__ __launch_bounds__(256)
void cvt_w1(const float* __restrict__ W, bf16* __restrict__ out)
{
    const int i = blockIdx.x * 256 + threadIdx.x;
    const float4 a = ((const float4*)W)[i * 2];
    const float4 b = ((const float4*)W)[i * 2 + 1];
    *(bf16x8*)&out[(size_t)i * 8] = cvt2(a, b);
}

__global__ __launch_bounds__(256)
void cvt_w3(const float* __restrict__ W0, const float* __restrict__ W1,
            const float* __restrict__ W2, bf16* __restrict__ out)
{
    const int z = blockIdx.y;
    const float* src = (z == 0) ? W0 : (z == 1) ? W1 : W2;
    const int i = blockIdx.x * 256 + threadIdx.x;          // < 131072
    const float4 a = ((const float4*)src)[i * 2];
    const float4 b = ((const float4*)src)[i * 2 + 1];
    *(bf16x8*)&out[((size_t)z << 20) + (size_t)i * 8] = cvt2(a, b);
}

// =====================================================================
// Merged projection GEMM, 128x128 tile, counted-vmcnt pipeline (T4):
// 4-deep ring of BK=32 half-tiles, depth-2 prefetch, raw s_barrier +
// inline s_waitcnt vmcnt(6) -- loads stay in flight ACROSS barriers
// (the round-1/2/4 binder was the vmcnt(0) drain before every barrier).
// grid (8, 64, 3), block 256 (4 waves, 2x2 of 64x64).
// A fp32: global->reg (issue at h, consumed cvt+ds_write at h+1);
// B bf16: ASYNC16 direct to LDS. Per-phase per-thread VMEM = 4 A-loads
// + 2 B-asyncs = 6; steady outstanding = 2 phases = 12 -> vmcnt(6)
// retires exactly phase h+1. lgkmcnt(0) before barrier publishes the
// ds_writes. Ring-4 + depth-2: issue(h+2) overwrites the buffer last
// read at h-2 (two barriers ago). rA reg sets indexed by literal parity
// (4-unrolled phases) to stay in registers.
// z=0: Qp = q*Wq^T ; z=1: Kp = k*Wk^T ; z=2: Vt = (v*Wv^T)^T [B,H,d,S]
// Key-mask early-exit for z>=1, block-uniform, precedes all barriers.
// =====================================================================
__global__ __launch_bounds__(256, 2)
void proj_gemm(const float* __restrict__ q, const float* __restrict__ k,
               const float* __restrict__ v, const bf16* __restrict__ Wb3,
               const int* __restrict__ sen_len,
               bf16* __restrict__ Qp, bf16* __restrict__ Kp, bf16* __restrict__ Vt)
{
    constexpr int K  = 1024;
    constexpr int NT = 32;                         // 32 phases of BK=32
    __shared__ __align__(16) bf16 Asr[4][128 * 32];
    __shared__ __align__(16) bf16 Bsr[4][128 * 32];

    const int z = blockIdx.z;
    const int flat = blockIdx.y * 8 + blockIdx.x;
    const int m0   = (flat & 63) * 128;   // same m-band -> same XCD
    const int n0   = (flat >> 6) * 128;

    if (z != 0) {
        const int s0 = m0 & 2047;
        if (s0 >= sen_len[m0 >> 11]) return;       // before any barrier
    }

    const float* A = (z == 0) ? q : (z == 1) ? k : v;
    const bf16* W = Wb3 + ((size_t)z << 20);

    const int tid  = threadIdx.x;
    const int lane = tid & 63;
    const int w    = tid >> 6;
    const int wr   = w >> 1, wc = w & 1;

    // staging geometry: 512 chunks of 8 elems cover 128x32; 2/thread.
    // chunk c: row=c>>2, kcols (c&3)*8..+7; LDS offset c*8 (row-major).
    // B dest = wave-uniform base + lane*16 (ASYNC16 constraint holds).
    const int c0 = tid,       r0 = c0 >> 2, g0 = c0 & 3;
    const int c1 = tid + 256, r1 = c1 >> 2, g1 = c1 & 3;
    const float* Ab0 = A + (size_t)(m0 + r0) * K + g0 * 8;
    const float* Ab1 = A + (size_t)(m0 + r1) * K + g1 * 8;
    const bf16*  Wb0 = W + (size_t)(n0 + r0) * K + g0 * 8;
    const bf16*  Wb1 = W + (size_t)(n0 + r1) * K + g1 * 8;

    float4 rA[2][4];          // 2 in-flight A reg-sets, literal-indexed
    f32x4 acc[4][4] = {};

#define P_ISSUE_A(ph, RI) do { \
        rA[RI][0] = *(const float4*)(Ab0 + (ph) * 32); \
        rA[RI][1] = *(const float4*)(Ab0 + (ph) * 32 + 4); \
        rA[RI][2] = *(const float4*)(Ab1 + (ph) * 32); \
        rA[RI][3] = *(const float4*)(Ab1 + (ph) * 32 + 4); } while (0)
#define P_ISSUE_B(ph, PI) do { \
        ASYNC16(Wb0 + (ph) * 32, &Bsr[PI][c0 * 8]); \
        ASYNC16(Wb1 + (ph) * 32, &Bsr[PI][c1 * 8]); } while (0)
#define P_WRITE_A(PW, RW) do { \
        *(bf16x8*)&Asr[PW][c0 * 8] = cvt2(rA[RW][0], rA[RW][1]); \
        *(bf16x8*)&Asr[PW][c1 * 8] = cvt2(rA[RW][2], rA[RW][3]); } while (0)
#define P_COMPUTE(PC) do { \
        bf16x8 af[4], bfr[4]; \
        _Pragma("unroll") \
        for (int t = 0; t < 4; ++t) { \
            af[t]  = *(const bf16x8*)&Asr[PC][(wr * 64 + t * 16 + (lane & 15)) * 32 + (lane >> 4) * 8]; \
            bfr[t] = *(const bf16x8*)&Bsr[PC][(wc * 64 + t * 16 + (lane & 15)) * 32 + (lane >> 4) * 8]; \
        } \
        _Pragma("unroll") \
        for (int mt = 0; mt < 4; ++mt) \
            _Pragma("unroll") \
            for (int nt = 0; nt < 4; ++nt) \
                acc[mt][nt] = __builtin_amdgcn_mfma_f32_16x16x32_bf16(af[mt], bfr[nt], acc[mt][nt], 0, 0, 0); \
    } while (0)

    // PC=h%4, PI=(h+2)%4, PW=(h+1)%4, RW=(h+1)&1, RI=h&1 (all literal)
#define P_PHASE(h, PC, PI, PW, RW, RI) do { \
        P_COMPUTE(PC); \
        if ((h) + 2 < NT) { P_ISSUE_A((h) + 2, RI); P_ISSUE_B((h) + 2, PI); } \
        if ((h) + 1 < NT) { \
            if ((h) + 2 < NT) { S_VMCNT(6); } else { S_VMCNT(0); } \
            P_WRITE_A(PW, RW); \
            S_LGKM0; S_BAR; \
        } } while (0)

    // prologue: phases 0,1 in flight; retire 0; publish A(0)
    P_ISSUE_A(0, 0); P_ISSUE_B(0, 0);
    P_ISSUE_A(1, 1); P_ISSUE_B(1, 1);
    S_VMCNT(6);
    P_WRITE_A(0, 0);
    S_LGKM0; S_BAR;

    for (int hb = 0; hb < NT; hb += 4) {
        P_PHASE(hb + 0, 0, 2, 1, 1, 0);
        P_PHASE(hb + 1, 1, 3, 2, 0, 1);
        P_PHASE(hb + 2, 2, 0, 3, 1, 0);
        P_PHASE(hb + 3, 3, 1, 0, 0, 1);
    }
#undef P_PHASE
#undef P_COMPUTE
#undef P_WRITE_A
#undef P_ISSUE_B
#undef P_ISSUE_A

    // epilogue: D[row][col], row=(lane>>4)*4+r, col=lane&15
    #pragma unroll
    for (int mt = 0; mt < 4; ++mt) {
        #pragma unroll
        for (int nt = 0; nt < 4; ++nt) {
            const int mbase = m0 + wr * 64 + mt * 16 + ((lane >> 4) << 2);
            const int n     = n0 + wc * 64 + nt * 16 + (lane & 15);
            if (z < 2) {
                bf16* out = (z == 0) ? Qp : Kp;     // row-major [M, 1024]
                #pragma unroll
                for (int r = 0; r < 4; ++r)
                    out[(size_t)(mbase + r) * 1024 + n] = (bf16)acc[mt][nt][r];
            } else {
                const int h = n >> 6, dd = n & 63;
                const int b = mbase >> 11, s = mbase & 2047;   // r=0..3 -> s..s+3
                bf16x4 v4;
                #pragma unroll
                for (int r = 0; r < 4; ++r) v4[r] = (bf16)acc[mt][nt][r];
                *(bf16x4*)&Vt[(((size_t)(b * 16 + h)) * 64 + dd) * 2048 + s] = v4;
            }
        }
    }
}

// =====================================================================
// Out-projection GEMM, 128x128, same counted-vmcnt pipeline (pure
// ASYNC16: 4 VMEM/phase -> steady vmcnt(4)). y = ctx * Wo^T + R.
// grid (8, 64), block 256.
// =====================================================================
__global__ __launch_bounds__(256, 2)
void gemm_out(const bf16* __restrict__ A, const bf16* __restrict__ W,
              const float* __restrict__ R, float* __restrict__ out)
{
    constexpr int K  = 1024;
    constexpr int NT = 32;
    __shared__ __align__(16) bf16 Asr[4][128 * 32];
    __shared__ __align__(16) bf16 Bsr[4][128 * 32];

    const int tid  = threadIdx.x;
    const int lane = tid & 63;
    const int w    = tid >> 6;
    const int wr   = w >> 1, wc = w & 1;
    const int flat = blockIdx.y * 8 + blockIdx.x;
    const int m0   = (flat & 63) * 128;
    const int n0   = (flat >> 6) * 128;

    const int c0 = tid,       r0 = c0 >> 2, g0 = c0 & 3;
    const int c1 = tid + 256, r1 = c1 >> 2, g1 = c1 & 3;
    const bf16* Ab0 = A + (size_t)(m0 + r0) * K + g0 * 8;
    const bf16* Ab1 = A + (size_t)(m0 + r1) * K + g1 * 8;
    const bf16* Wb0 = W + (size_t)(n0 + r0) * K + g0 * 8;
    const bf16* Wb1 = W + (size_t)(n0 + r1) * K + g1 * 8;

    f32x4 acc[4][4] = {};

#define G_ISSUE(ph, PI) do { \
        ASYNC16(Ab0 + (ph) * 32, &Asr[PI][c0 * 8]); \
        ASYNC16(Ab1 + (ph) * 32, &Asr[PI][c1 * 8]); \
        ASYNC16(Wb0 + (ph) * 32, &Bsr[PI][c0 * 8]); \
        ASYNC16(Wb1 + (ph) * 32, &Bsr[PI][c1 * 8]); } while (0)
#define G_COMPUTE(PC) do { \
        bf16x8 af[4], bfr[4]; \
        _Pragma("unroll") \
        for (int t = 0; t < 4; ++t) { \
            af[t]  = *(const bf16x8*)&Asr[PC][(wr * 64 + t * 16 + (lane & 15)) * 32 + (lane >> 4) * 8]; \
            bfr[t] = *(const bf16x8*)&Bsr[PC][(wc * 64 + t * 16 + (lane & 15)) * 32 + (lane >> 4) * 8]; \
        } \
        _Pragma("unroll") \
        for (int mt = 0; mt < 4; ++mt) \
            _Pragma("unroll") \
            for (int nt = 0; nt < 4; ++nt) \
                acc[mt][nt] = __builtin_amdgcn_mfma_f32_16x16x32_bf16(af[mt], bfr[nt], acc[mt][nt], 0, 0, 0); \
    } while (0)
#define G_PHASE(h, PC, PI) do { \
        G_COMPUTE(PC); \
        if ((h) + 2 < NT) { G_ISSUE((h) + 2, PI); } \
        if ((h) + 1 < NT) { \
            if ((h) + 2 < NT) { S_VMCNT(4); } else { S_VMCNT(0); } \
            S_BAR; \
        } } while (0)

    G_ISSUE(0, 0);
    G_ISSUE(1, 1);
    S_VMCNT(4);
    S_BAR;

    for (int hb = 0; hb < NT; hb += 4) {
        G_PHASE(hb + 0, 0, 2);
        G_PHASE(hb + 1, 1, 3);
        G_PHASE(hb + 2, 2, 0);
        G_PHASE(hb + 3, 3, 1);
    }
#undef G_PHASE
#undef G_COMPUTE
#undef G_ISSUE

    #pragma unroll
    for (int mt = 0; mt < 4; ++mt) {
        #pragma unroll
        for (int nt = 0; nt < 4; ++nt) {
            const int mbase = m0 + wr * 64 + mt * 16 + ((lane >> 4) << 2);
            const int n     = n0 + wc * 64 + nt * 16 + (lane & 15);
            #pragma unroll
            for (int r = 0; r < 4; ++r) {
                const size_t idx = (size_t)(mbase + r) * 1024 + n;
                out[idx] = acc[mt][nt][r] + R[idx];
            }
        }
    }
}

// =====================================================================
// Flash attention, static-max. block 256 (4 waves), grid (16,16,4).
// Qp,Kp: [B,S,D] bf16 (head-cols h*64..h*64+63); Vt: [B,H,d,S] bf16;
// ctx out: [B,S,H*64] bf16. softmax = exp(S*scale-20)/sum (exact).
// =====================================================================
__global__ __launch_bounds__(256, 2)
void attn_kernel(const bf16* __restrict__ Qp, const bf16* __restrict__ Kp,
                 const bf16* __restrict__ Vt, const int* __restrict__ sen_len,
                 bf16* __restrict__ ctx)
{
    const int qt = gridDim.x - 1 - blockIdx.x;   // longest blocks first
    const int h = blockIdx.y, b = blockIdx.z;
    const int q0 = qt * 128;
    const int slen = sen_len[b];
    const int tid = threadIdx.x, lane = tid & 63, w = tid >> 6;
    const int wr = w >> 1, wc = w & 1;
    const float SCALE = 0.125f;   // 1/sqrt(64)
    const float SHIFT = 20.0f;    // static softmax shift

    __shared__ __align__(16) bf16 Ps[128 * 136];   // [q][k] probs, padded
    __shared__ float psum[2][128];

    // Q fragments (A-operand: m=lane&15, k=(lane>>4)*8+j)
    bf16x8 qf[4][2];
    const bf16* Qbase = Qp + ((size_t)(b * 2048 + q0)) * 1024 + h * 64;
    #pragma unroll
    for (int mt = 0; mt < 4; ++mt)
        #pragma unroll
        for (int kk = 0; kk < 2; ++kk)
            qf[mt][kk] = *(const bf16x8*)(Qbase + (size_t)(wr * 64 + mt * 16 + (lane & 15)) * 1024
                                          + kk * 32 + (lane >> 4) * 8);

    f32x4 o[4][2] = {};
    float lsum[4][4] = {};   // per-lane partial row sums, reduced at end

    const int jlim = min(q0 + 128, slen);
    const int nkt  = (jlim + 127) >> 7;       // >= 1 since slen >= 1

    const bf16* Kbh = Kp + (size_t)b * 2048 * 1024 + h * 64;
    const bf16* Vbh = Vt + (size_t)(b * 16 + h) * 64 * 2048;

    for (int kt = 0; kt < nkt; ++kt) {
        const int k0 = kt * 128;

        // ---- S = Q K^T (K fragments direct from global, 16B/lane) ----
        f32x4 sf[4][4] = {};
        #pragma unroll
        for (int kk = 0; kk < 2; ++kk) {
            bf16x8 bk[4];
            #pragma unroll
            for (int nt = 0; nt < 4; ++nt)
                bk[nt] = *(const bf16x8*)(Kbh + (size_t)(k0 + wc * 64 + nt * 16 + (lane & 15)) * 1024
                                          + kk * 32 + (lane >> 4) * 8);
            #pragma unroll
            for (int mt = 0; mt < 4; ++mt)
                #pragma unroll
                for (int nt = 0; nt < 4; ++nt)
                    sf[mt][nt] = __builtin_amdgcn_mfma_f32_16x16x32_bf16(qf[mt][kk], bk[nt], sf[mt][nt], 0, 0, 0);
        }

        // ---- P = exp(S*scale - 20); accumulate l; store P to LDS ----
        if (kt == nkt - 1) {
            #pragma unroll
            for (int mt = 0; mt < 4; ++mt)
                #pragma unroll
                for (int r = 0; r < 4; ++r) {
                    const int row = wr * 64 + mt * 16 + ((lane >> 4) << 2) + r;
                    const int ig = q0 + row;
                    #pragma unroll
                    for (int nt = 0; nt < 4; ++nt) {
                        const int jg = k0 + wc * 64 + nt * 16 + (lane & 15);
                        const float sv = (jg > ig || jg >= slen) ? -1.0e9f : sf[mt][nt][r];
                        const float p = __expf(fmaf(sv, SCALE, -SHIFT));
                        lsum[mt][r] += p;
                        Ps[row * 136 + wc * 64 + nt * 16 + (lane & 15)] = (bf16)p;
                    }
                }
        } else {
            #pragma unroll
            for (int mt = 0; mt < 4; ++mt)
                #pragma unroll
                for (int r = 0; r < 4; ++r) {
                    const int row = wr * 64 + mt * 16 + ((lane >> 4) << 2) + r;
                    #pragma unroll
                    for (int nt = 0; nt < 4; ++nt) {
                        const float p = __expf(fmaf(sf[mt][nt][r], SCALE, -SHIFT));
                        lsum[mt][r] += p;
                        Ps[row * 136 + wc * 64 + nt * 16 + (lane & 15)] = (bf16)p;
                    }
                }
        }
        __syncthreads();   // Ps ready for PV

        // ---- O += P V (V fragments direct from global, 16B/lane) ----
        #pragma unroll
        for (int ks = 0; ks < 4; ++ks) {
            bf16x8 pf[4], vf[2];
            #pragma unroll
            for (int mt = 0; mt < 4; ++mt)
                pf[mt] = *(const bf16x8*)&Ps[(wr * 64 + mt * 16 + (lane & 15)) * 136
                                             + ks * 32 + (lane >> 4) * 8];
            #pragma unroll
            for (int nt = 0; nt < 2; ++nt)
                vf[nt] = *(const bf16x8*)(Vbh + (size_t)(wc * 32 + nt * 16 + (lane & 15)) * 2048
                                          + k0 + ks * 32 + (lane >> 4) * 8);
            #pragma unroll
            for (int mt = 0; mt < 4; ++mt)
                #pragma unroll
                for (int nt = 0; nt < 2; ++nt)
                    o[mt][nt] = __builtin_amdgcn_mfma_f32_16x16x32_bf16(pf[mt], vf[nt], o[mt][nt], 0, 0, 0);
        }
        __syncthreads();   // protect Ps for next iteration
    }

    // ---- one-time l reduction ----
    #pragma unroll
    for (int off = 1; off < 16; off <<= 1)
        #pragma unroll
        for (int mt = 0; mt < 4; ++mt)
            #pragma unroll
            for (int r = 0; r < 4; ++r)
                lsum[mt][r] += __shfl_xor(lsum[mt][r], off, 64);
    if ((lane & 15) == 0)
        #pragma unroll
        for (int mt = 0; mt < 4; ++mt)
            #pragma unroll
            for (int r = 0; r < 4; ++r)
                psum[wc][wr * 64 + mt * 16 + ((lane >> 4) << 2) + r] = lsum[mt][r];
    __syncthreads();

    // ---- epilogue: ctx[b, s, h*64+dd] = O / l ----
    #pragma unroll
    for (int mt = 0; mt < 4; ++mt)
        #pragma unroll
        for (int r = 0; r < 4; ++r) {
            const int row = wr * 64 + mt * 16 + ((lane >> 4) << 2) + r;
            const float inv = 1.0f / (psum[0][row] + psum[1][row]);
            const int sg = q0 + row;
            #pragma unroll
            for (int nt = 0; nt < 2; ++nt) {
                const int dd = wc * 32 + nt * 16 + (lane & 15);
                ctx[((size_t)(b * 2048 + sg)) * 1024 + h * 64 + dd] = (bf16)(o[mt][nt][r] * inv);
            }
        }
}

// =====================================================================
// LayerNorm over D=1024; fp32 in/out. grid 8192, block 256.
// =====================================================================
__global__ __launch_bounds__(256)
void ln_kernel(const float* __restrict__ y, const float* __restrict__ gamma,
               const float* __restrict__ beta, float* __restrict__ out)
{
    const int row = blockIdx.x;
    const int tid = threadIdx.x;
    const float4 v = ((const float4*)(y + (size_t)row * 1024))[tid];
    float s  = v.x + v.y + v.z + v.w;
    float s2 = v.x * v.x + v.y * v.y + v.z * v.z + v.w * v.w;
    #pragma unroll
    for (int o = 32; o > 0; o >>= 1) {
        s  += __shfl_down(s, o, 64);
        s2 += __shfl_down(s2, o, 64);
    }
    __shared__ float ps[4], ps2[4], stat[2];
    const int w = tid >> 6, lane = tid & 63;
    if (lane == 0) { ps[w] = s; ps2[w] = s2; }
    __syncthreads();
    if (tid == 0) {
        const float S  = ps[0] + ps[1] + ps[2] + ps[3];
        const float S2 = ps2[0] + ps2[1] + ps2[2] + ps2[3];
        const float mean = S * (1.0f / 1024.0f);
        const float var  = S2 * (1.0f / 1024.0f) - mean * mean;
        stat[0] = mean;
        stat[1] = rsqrtf(var + 1e-5f);
    }
    __syncthreads();
    const float mean = stat[0], rstd = stat[1];
    const float4 g4 = ((const float4*)gamma)[tid];
    const float4 b4 = ((const float4*)beta)[tid];
    float4 ov;
    ov.x = (v.x - mean) * rstd * g4.x + b4.x;
    ov.y = (v.y - mean) * rstd * g4.y + b4.y;
    ov.z = (v.z - mean) * rstd * g4.z + b4.z;
    ov.w = (v.w - mean) * rstd * g4.w + b4.w;
    ((float4*)(out + (size_t)row * 1024))[tid] = ov;
}

// =====================================================================
// Workspace map (peak 56.4 MB):
//   ws[0,SEG):       Qp [B,S,D] -> y fp32 [0,2SEG) after attn
//   ws[SEG,2SEG):    Kp [B,S,D]
//   ws[2SEG,3SEG):   Vt [B,H,d,S]
//   ws[3SEG,+6MB):   Wb3 (Wq,Wk,Wv bf16); first 2MB reused as WoB later
//   d_out[0,SEG):    ctx (attn out) -> final LN out (LN rewrites all d_out)
// =====================================================================
extern "C" void kernel_launch(void* const* d_in, const int* in_sizes, int n_in,
                              void* d_out, int out_size, void* d_ws, size_t ws_size,
                              hipStream_t stream)
{
    const float* q     = (const float*)d_in[0];
    const float* k     = (const float*)d_in[1];
    const float* v     = (const float*)d_in[2];
    const float* Wq    = (const float*)d_in[3];
    const float* Wk    = (const float*)d_in[4];
    const float* Wv    = (const float*)d_in[5];
    const float* Wo    = (const float*)d_in[6];
    const float* gamma = (const float*)d_in[7];
    const float* beta  = (const float*)d_in[8];
    const int*   sen   = (const int*)d_in[9];

    char* ws = (char*)d_ws;
    const size_t SEG = 16777216;             // 8192*1024*2 bytes
    bf16* Qp  = (bf16*)(ws);
    bf16* Kp  = (bf16*)(ws + SEG);
    bf16* Vt  = (bf16*)(ws + 2 * SEG);
    bf16* Wb3 = (bf16*)(ws + 3 * SEG);
    bf16* WoB = (bf16*)(ws + 3 * SEG);       // reuses Wb3 (dead after proj)
    float* y  = (float*)ws;                  // overwrites Qp/Kp after attn
    bf16* ctx = (bf16*)d_out;                // d_out as scratch; LN rewrites

    dim3 bb(256);
    cvt_w3<<<dim3(512, 3), bb, 0, stream>>>(Wq, Wk, Wv, Wb3);
    proj_gemm<<<dim3(8, 64, 3), bb, 0, stream>>>(q, k, v, Wb3, sen, Qp, Kp, Vt);
    attn_kernel<<<dim3(16, 16, 4), bb, 0, stream>>>(Qp, Kp, Vt, sen, ctx);
    cvt_w1<<<dim3(512), bb, 0, stream>>>(Wo, WoB);
    gemm_out<<<dim3(8, 64), bb, 0, stream>>>(ctx, WoB, q, y);
    ln_kernel<<<dim3(8192), bb, 0, stream>>>(y, gamma, beta, (float*)d_out);
}